// Round 11
// baseline (64.760 us; speedup 1.0000x reference)
//
#include <hip/hip_runtime.h>
#include <cstdint>

// NT-Xent: B=4096, D=128, N=8192, T=0.5
// loss = mean_i( log(sum_{j!=i} exp(sim_ij/T)) - sim_{i,(i+B)%N}/T )
//
// R10 -> R11: exploit sim symmetry -- compute only block-lower-triangle,
// export rowsums AND colsums (work x0.516). 528 pairs x 2 col-halves =
// 1056 blocks of 256rows x 128cols (3 blocks/CU regime kept). nt=4,
// fully unrolled, 4 distinct LDS buffers, vmcnt ladder 4/4/2/0.
// Partial slots: rowsum slot=2*by+h, colsum slot=64+bx (unique, no init).

#define BROWS 4096
#define NROWS 8192
#define ROWB  256          // bytes per bf16 row
#define TILEB 8192         // bytes per 32-col B tile
#define NSLOT 96

typedef __attribute__((ext_vector_type(8))) __bf16    bf16x8;
typedef __attribute__((ext_vector_type(4))) float     f32x4;
typedef __attribute__((ext_vector_type(4))) uint32_t  u32x4;

#define K1F 2.8853900817779268f   // (1/T)*log2(e)
#define LN2F 0.69314718055994531f
#define BC8(x) __builtin_bit_cast(bf16x8, x)

__device__ __forceinline__ uint16_t f2bf(float f) {
    uint32_t u = __builtin_bit_cast(uint32_t, f);
    u = (u + 0x7FFFu + ((u >> 16) & 1u)) >> 16;
    return (uint16_t)u;
}
__device__ __forceinline__ float bf2f(uint16_t b) {
    return __builtin_bit_cast(float, ((uint32_t)b) << 16);
}
__device__ __forceinline__ void gload_lds16(const void* g, void* l) {
    __builtin_amdgcn_global_load_lds(
        (const __attribute__((address_space(1))) void*)g,
        (__attribute__((address_space(3))) void*)l, 16, 0, 0);
}

// ---- kernel 1: L2-normalize rows; emit znB = bf16(x^), znA = bf16(K1*x^) ----
__global__ __launch_bounds__(256) void k_normalize(
    const float* __restrict__ zi, const float* __restrict__ zj,
    uint16_t* __restrict__ znA, uint16_t* __restrict__ znB)
{
    int tid  = threadIdx.x;
    int lane = tid & 63;
    int wid  = tid >> 6;
    int li   = lane & 7;
    int row  = blockIdx.x * 32 + wid * 8 + (lane >> 3);

    const float* src = (row < BROWS) ? (zi + (size_t)row * 128)
                                     : (zj + (size_t)(row - BROWS) * 128);
    float4 v[4];
    const float4* s4 = (const float4*)(src + li * 16);
#pragma unroll
    for (int c = 0; c < 4; ++c) v[c] = s4[c];

    float ss = 0.f;
#pragma unroll
    for (int c = 0; c < 4; ++c)
        ss += v[c].x*v[c].x + v[c].y*v[c].y + v[c].z*v[c].z + v[c].w*v[c].w;
#pragma unroll
    for (int off = 1; off < 8; off <<= 1) ss += __shfl_xor(ss, off);

    float scale = 1.0f / fmaxf(sqrtf(ss), 1e-8f);

    float e[16];
#pragma unroll
    for (int c = 0; c < 4; ++c) {
        e[c*4+0] = v[c].x * scale; e[c*4+1] = v[c].y * scale;
        e[c*4+2] = v[c].z * scale; e[c*4+3] = v[c].w * scale;
    }
    uint32_t wB[8], wA[8];
#pragma unroll
    for (int q = 0; q < 8; ++q) {
        wB[q] = (uint32_t)f2bf(e[2*q])       | ((uint32_t)f2bf(e[2*q+1])       << 16);
        wA[q] = (uint32_t)f2bf(e[2*q] * K1F) | ((uint32_t)f2bf(e[2*q+1] * K1F) << 16);
    }
    uint4* dB = (uint4*)((char*)znB + (size_t)row * ROWB + li * 32);
    dB[0] = make_uint4(wB[0], wB[1], wB[2], wB[3]);
    dB[1] = make_uint4(wB[4], wB[5], wB[6], wB[7]);
    uint4* dA = (uint4*)((char*)znA + (size_t)row * ROWB + li * 32);
    dA[0] = make_uint4(wA[0], wA[1], wA[2], wA[3]);
    dA[1] = make_uint4(wA[4], wA[5], wA[6], wA[7]);
}

// ---- kernel 2: triangular sim blocks, rowsum + colsum export ----------------
// grid 1056 = (528 lower-tri pairs) x (2 col-halves); block 256 thr = 4 waves.
// Block: rows bx*256..+256, cols by*256 + h*128..+128 (4 x 32-col tiles).
__global__ __launch_bounds__(256)
__attribute__((amdgpu_waves_per_eu(3, 3)))
void k_simlse(
    const uint16_t* __restrict__ znA, const uint16_t* __restrict__ znB,
    float* __restrict__ partial)
{
    __shared__ __align__(16) char lds[4][TILEB];   // 32 KB, 4 distinct buffers
    __shared__ float cslds[4 * 128];               // 2 KB colsum xwave buffer

    const char* zA = (const char*)znA;
    const char* zB = (const char*)znB;
    int tid  = threadIdx.x;
    int lane = tid & 63;
    int wid  = tid >> 6;
    int lo16 = lane & 15;
    int hi4  = lane >> 4;

    // decode triangle pair: p in [0,528) -> (bx >= by)
    int q = blockIdx.x;
    int p = q >> 1, h = q & 1;
    int s = p / 33, w = p % 33;
    int bx, by;
    if (w < 32 - s) { by = s;      bx = s + w; }
    else            { by = 31 - s; bx = by + (w - (32 - s)); }

    int rowBase = bx * 256 + wid * 64;

    // A fragments (prescaled by K1): 4 row-tiles x 4 K-frags = 64 regs.
    u32x4 a[4][4];
#pragma unroll
    for (int rt = 0; rt < 4; ++rt) {
        const char* ap = zA + (size_t)(rowBase + rt * 16 + lo16) * ROWB + hi4 * 16;
#pragma unroll
        for (int kf = 0; kf < 4; ++kf)
            a[rt][kf] = *(const u32x4*)(ap + kf * 64);
    }

    float rs[4][4];
#pragma unroll
    for (int rt = 0; rt < 4; ++rt)
#pragma unroll
        for (int r = 0; r < 4; ++r) rs[rt][r] = 0.f;
    float cs[8];
#pragma unroll
    for (int tg = 0; tg < 8; ++tg) cs[tg] = 0.f;

    // B staging: 4 x 32-col tiles starting at tile index by*8 + h*4
    const char* gsrc = zB + (size_t)(by * 8 + h * 4) * TILEB
                     + ((tid * 16) ^ (((tid >> 4) & 7) << 4));
    int xorv = (lo16 & 7) << 4;        // read-side swizzle

#define STAGE(sel) do {                                                        \
        const char* g_ = gsrc + (size_t)(sel) * TILEB;                         \
        gload_lds16(g_,        &lds[sel][wid * 1024]);                         \
        gload_lds16(g_ + 4096, &lds[sel][4096 + wid * 1024]);                  \
    } while (0)

#define SUBTILE(sel, ct, TG) do {                                              \
        const char* lb_ = &lds[sel][(ct) * 4096 + lo16 * 256];                 \
        u32x4 bf0 = *(const u32x4*)(lb_ + ((hi4 * 16 +   0) ^ xorv));          \
        u32x4 bf1 = *(const u32x4*)(lb_ + ((hi4 * 16 +  64) ^ xorv));          \
        u32x4 bf2 = *(const u32x4*)(lb_ + ((hi4 * 16 + 128) ^ xorv));          \
        u32x4 bf3 = *(const u32x4*)(lb_ + ((hi4 * 16 + 192) ^ xorv));          \
        f32x4 A0 = {0.f,0.f,0.f,0.f}, A1 = {0.f,0.f,0.f,0.f};                  \
        f32x4 A2 = {0.f,0.f,0.f,0.f}, A3 = {0.f,0.f,0.f,0.f};                  \
        A0 = __builtin_amdgcn_mfma_f32_16x16x32_bf16(BC8(a[0][0]), BC8(bf0), A0, 0, 0, 0); \
        A1 = __builtin_amdgcn_mfma_f32_16x16x32_bf16(BC8(a[1][0]), BC8(bf0), A1, 0, 0, 0); \
        A2 = __builtin_amdgcn_mfma_f32_16x16x32_bf16(BC8(a[2][0]), BC8(bf0), A2, 0, 0, 0); \
        A3 = __builtin_amdgcn_mfma_f32_16x16x32_bf16(BC8(a[3][0]), BC8(bf0), A3, 0, 0, 0); \
        A0 = __builtin_amdgcn_mfma_f32_16x16x32_bf16(BC8(a[0][1]), BC8(bf1), A0, 0, 0, 0); \
        A1 = __builtin_amdgcn_mfma_f32_16x16x32_bf16(BC8(a[1][1]), BC8(bf1), A1, 0, 0, 0); \
        A2 = __builtin_amdgcn_mfma_f32_16x16x32_bf16(BC8(a[2][1]), BC8(bf1), A2, 0, 0, 0); \
        A3 = __builtin_amdgcn_mfma_f32_16x16x32_bf16(BC8(a[3][1]), BC8(bf1), A3, 0, 0, 0); \
        A0 = __builtin_amdgcn_mfma_f32_16x16x32_bf16(BC8(a[0][2]), BC8(bf2), A0, 0, 0, 0); \
        A1 = __builtin_amdgcn_mfma_f32_16x16x32_bf16(BC8(a[1][2]), BC8(bf2), A1, 0, 0, 0); \
        A2 = __builtin_amdgcn_mfma_f32_16x16x32_bf16(BC8(a[2][2]), BC8(bf2), A2, 0, 0, 0); \
        A3 = __builtin_amdgcn_mfma_f32_16x16x32_bf16(BC8(a[3][2]), BC8(bf2), A3, 0, 0, 0); \
        A0 = __builtin_amdgcn_mfma_f32_16x16x32_bf16(BC8(a[0][3]), BC8(bf3), A0, 0, 0, 0); \
        A1 = __builtin_amdgcn_mfma_f32_16x16x32_bf16(BC8(a[1][3]), BC8(bf3), A1, 0, 0, 0); \
        A2 = __builtin_amdgcn_mfma_f32_16x16x32_bf16(BC8(a[2][3]), BC8(bf3), A2, 0, 0, 0); \
        A3 = __builtin_amdgcn_mfma_f32_16x16x32_bf16(BC8(a[3][3]), BC8(bf3), A3, 0, 0, 0); \
        float cst = 0.f;                                                       \
        _Pragma("unroll")                                                      \
        for (int r = 0; r < 4; ++r) {                                          \
            float e0 = __builtin_amdgcn_exp2f(A0[r]); rs[0][r] += e0;          \
            float e1 = __builtin_amdgcn_exp2f(A1[r]); rs[1][r] += e1;          \
            float e2 = __builtin_amdgcn_exp2f(A2[r]); rs[2][r] += e2;          \
            float e3 = __builtin_amdgcn_exp2f(A3[r]); rs[3][r] += e3;          \
            cst += (e0 + e1) + (e2 + e3);                                      \
        }                                                                      \
        cs[TG] += cst;                                                         \
    } while (0)

#define WAITBAR(n) do {                                                       \
        asm volatile("s_waitcnt vmcnt(" #n ")" ::: "memory");                  \
        __builtin_amdgcn_s_barrier();                                          \
        __builtin_amdgcn_sched_barrier(0);                                     \
    } while (0)

    STAGE(0); STAGE(1); STAGE(2);          // 6 loads in flight
    WAITBAR(4); SUBTILE(0, 0, 0); SUBTILE(0, 1, 1); STAGE(3);
    WAITBAR(4); SUBTILE(1, 0, 2); SUBTILE(1, 1, 3);
    WAITBAR(2); SUBTILE(2, 0, 4); SUBTILE(2, 1, 5);
    WAITBAR(0); SUBTILE(3, 0, 6); SUBTILE(3, 1, 7);

#undef STAGE
#undef SUBTILE
#undef WAITBAR

    // rowsum export: reduce across the 16 column-lanes -> slot 2*by+h
#pragma unroll
    for (int rt = 0; rt < 4; ++rt)
#pragma unroll
        for (int r = 0; r < 4; ++r) {
            float v = rs[rt][r];
            v += __shfl_xor(v, 1);  v += __shfl_xor(v, 2);
            v += __shfl_xor(v, 4);  v += __shfl_xor(v, 8);
            if (lo16 == 0) {
                int row = rowBase + rt * 16 + hi4 * 4 + r;
                partial[(size_t)(2 * by + h) * NROWS + row] = v;
            }
        }

    // colsum export (off-diagonal only): slot 64+bx, cols by*256+h*128+[0,128)
    if (bx != by) {
#pragma unroll
        for (int tg = 0; tg < 8; ++tg) {
            float v = cs[tg];
            v += __shfl_xor(v, 16);
            v += __shfl_xor(v, 32);
            if (hi4 == 0) cslds[wid * 128 + tg * 16 + lo16] = v;
        }
        __syncthreads();
        if (tid < 128) {
            float v = (cslds[tid] + cslds[128 + tid])
                    + (cslds[256 + tid] + cslds[384 + tid]);
            partial[(size_t)(64 + bx) * NROWS + by * 256 + h * 128 + tid] = v;
        }
    }
}

// ---- kernel 3: per-row lse - pos, subtract diag, block partial sums --------
// block b covers rows [256b, 256b+256) -> R = b; valid slots: 0..2R+1 (rowsum)
// and 64+b' for b' > R (colsum).
__global__ __launch_bounds__(256) void k_finalize(
    const uint16_t* __restrict__ znA, const uint16_t* __restrict__ znB,
    const float* __restrict__ partial, float* __restrict__ blocksum)
{
    int tid = threadIdx.x;
    int R = blockIdx.x;
    int i = R * 256 + tid;

    float S = 0.f;
    for (int s2 = 0; s2 < 2 * (R + 1); ++s2)
        S += partial[(size_t)s2 * NROWS + i];
    for (int b = R + 1; b < 32; ++b)
        S += partial[(size_t)(64 + b) * NROWS + i];

    int j = (i + BROWS) & (NROWS - 1);
    const uint4* rAi = (const uint4*)((const char*)znA + (size_t)i * ROWB);
    const uint4* rBi = (const uint4*)((const char*)znB + (size_t)i * ROWB);
    const uint4* rBj = (const uint4*)((const char*)znB + (size_t)j * ROWB);
    float adot = 0.f;   // K1 * <zn_i, zn_j>
    float sdot = 0.f;   // K1 * <zn_i, zn_i>
#pragma unroll
    for (int c = 0; c < 16; ++c) {
        uint4 ua = rAi[c], ub = rBi[c], vb = rBj[c];
        const uint32_t* pa = (const uint32_t*)&ua;
        const uint32_t* pb = (const uint32_t*)&ub;
        const uint32_t* pv = (const uint32_t*)&vb;
#pragma unroll
        for (int qq = 0; qq < 4; ++qq) {
            float a0 = bf2f((uint16_t)(pa[qq] & 0xffffu)), a1 = bf2f((uint16_t)(pa[qq] >> 16));
            float b0 = bf2f((uint16_t)(pb[qq] & 0xffffu)), b1 = bf2f((uint16_t)(pb[qq] >> 16));
            float v0 = bf2f((uint16_t)(pv[qq] & 0xffffu)), v1 = bf2f((uint16_t)(pv[qq] >> 16));
            adot += a0 * v0 + a1 * v1;
            sdot += a0 * b0 + a1 * b1;
        }
    }
    S -= __builtin_amdgcn_exp2f(sdot);                  // remove diagonal term
    float c = LN2F * (__builtin_amdgcn_logf(S) - adot); // ln(S) - pos/T

#pragma unroll
    for (int off = 1; off < 64; off <<= 1) c += __shfl_xor(c, off);
    __shared__ float wsum[4];
    int lane = tid & 63, wid = tid >> 6;
    if (lane == 0) wsum[wid] = c;
    __syncthreads();
    if (tid == 0) blocksum[blockIdx.x] = wsum[0] + wsum[1] + wsum[2] + wsum[3];
}

// ---- kernel 4: final scalar -------------------------------------------------
__global__ __launch_bounds__(64) void k_reduce(
    const float* __restrict__ blocksum, float* __restrict__ out)
{
    int tid = threadIdx.x;
    float v = (tid < 32) ? blocksum[tid] : 0.f;
#pragma unroll
    for (int off = 1; off < 64; off <<= 1) v += __shfl_xor(v, off);
    if (tid == 0) out[0] = v * (1.0f / (float)NROWS);
}

extern "C" void kernel_launch(void* const* d_in, const int* in_sizes, int n_in,
                              void* d_out, int out_size, void* d_ws, size_t ws_size,
                              hipStream_t stream)
{
    const float* zi = (const float*)d_in[0];
    const float* zj = (const float*)d_in[1];
    float* out = (float*)d_out;

    char* ws = (char*)d_ws;
    uint16_t* znA      = (uint16_t*)ws;                                   // 2 MB
    uint16_t* znB      = (uint16_t*)(ws + (size_t)NROWS * ROWB);          // 2 MB
    float*    partial  = (float*)(ws + 2 * (size_t)NROWS * ROWB);         // 3 MB
    float*    blocksum = (float*)(ws + 2 * (size_t)NROWS * ROWB
                                     + (size_t)NSLOT * NROWS * 4);

    k_normalize<<<dim3(256), dim3(256), 0, stream>>>(zi, zj, znA, znB);
    k_simlse  <<<dim3(1056), dim3(256), 0, stream>>>(znA, znB, partial);
    k_finalize<<<dim3(32), dim3(256), 0, stream>>>(znA, znB, partial, blocksum);
    k_reduce  <<<dim3(1), dim3(64), 0, stream>>>(blocksum, out);
}

// Round 12
// 49.648 us; speedup vs baseline: 1.3044x; 1.3044x over previous
//
#include <hip/hip_runtime.h>
#include <cstdint>

// NT-Xent: B=4096, D=128, N=8192, T=0.5
// loss = mean_i( log(sum_{j!=i} exp(sim_ij/T)) - sim_{i,(i+B)%N}/T )
//
// R11 -> R12: revert symmetry (regressed 64.8us; extra live state / residency
// tail). Test the per-round-overhead model cleanly: 64-col rounds (2x work
// per barrier round), ring-3 x 16KB LDS, same grid/wave/register shape as the
// proven R9 skeleton. Rounds per block 10.67 -> 5.33.

#define BROWS 4096
#define NROWS 8192
#define ROWB  256          // bytes per bf16 row
#define CSPL  24           // column splits: 32 rowblocks x 24 = 768 blocks
#define CT64  128          // 8192/64 column tiles (64-col rounds)
#define BRT   256          // rows per block (4 waves x 64)
#define TILEB 16384        // bytes per 64-col B tile

typedef __attribute__((ext_vector_type(8))) __bf16    bf16x8;
typedef __attribute__((ext_vector_type(4))) float     f32x4;
typedef __attribute__((ext_vector_type(4))) uint32_t  u32x4;

#define K1F 2.8853900817779268f   // (1/T)*log2(e)
#define LN2F 0.69314718055994531f
#define BC8(x) __builtin_bit_cast(bf16x8, x)

__device__ __forceinline__ uint16_t f2bf(float f) {
    uint32_t u = __builtin_bit_cast(uint32_t, f);
    u = (u + 0x7FFFu + ((u >> 16) & 1u)) >> 16;
    return (uint16_t)u;
}
__device__ __forceinline__ float bf2f(uint16_t b) {
    return __builtin_bit_cast(float, ((uint32_t)b) << 16);
}
__device__ __forceinline__ void gload_lds16(const void* g, void* l) {
    __builtin_amdgcn_global_load_lds(
        (const __attribute__((address_space(1))) void*)g,
        (__attribute__((address_space(3))) void*)l, 16, 0, 0);
}

// ---- kernel 1: L2-normalize rows; emit znB = bf16(x^), znA = bf16(K1*x^) ----
__global__ __launch_bounds__(256) void k_normalize(
    const float* __restrict__ zi, const float* __restrict__ zj,
    uint16_t* __restrict__ znA, uint16_t* __restrict__ znB)
{
    int tid  = threadIdx.x;
    int lane = tid & 63;
    int wid  = tid >> 6;
    int li   = lane & 7;
    int row  = blockIdx.x * 32 + wid * 8 + (lane >> 3);

    const float* src = (row < BROWS) ? (zi + (size_t)row * 128)
                                     : (zj + (size_t)(row - BROWS) * 128);
    float4 v[4];
    const float4* s4 = (const float4*)(src + li * 16);
#pragma unroll
    for (int c = 0; c < 4; ++c) v[c] = s4[c];

    float ss = 0.f;
#pragma unroll
    for (int c = 0; c < 4; ++c)
        ss += v[c].x*v[c].x + v[c].y*v[c].y + v[c].z*v[c].z + v[c].w*v[c].w;
#pragma unroll
    for (int off = 1; off < 8; off <<= 1) ss += __shfl_xor(ss, off);

    float scale = 1.0f / fmaxf(sqrtf(ss), 1e-8f);

    float e[16];
#pragma unroll
    for (int c = 0; c < 4; ++c) {
        e[c*4+0] = v[c].x * scale; e[c*4+1] = v[c].y * scale;
        e[c*4+2] = v[c].z * scale; e[c*4+3] = v[c].w * scale;
    }
    uint32_t wB[8], wA[8];
#pragma unroll
    for (int q = 0; q < 8; ++q) {
        wB[q] = (uint32_t)f2bf(e[2*q])       | ((uint32_t)f2bf(e[2*q+1])       << 16);
        wA[q] = (uint32_t)f2bf(e[2*q] * K1F) | ((uint32_t)f2bf(e[2*q+1] * K1F) << 16);
    }
    uint4* dB = (uint4*)((char*)znB + (size_t)row * ROWB + li * 32);
    dB[0] = make_uint4(wB[0], wB[1], wB[2], wB[3]);
    dB[1] = make_uint4(wB[4], wB[5], wB[6], wB[7]);
    uint4* dA = (uint4*)((char*)znA + (size_t)row * ROWB + li * 32);
    dA[0] = make_uint4(wA[0], wA[1], wA[2], wA[3]);
    dA[1] = make_uint4(wA[4], wA[5], wA[6], wA[7]);
}

// ---- kernel 2: LDS-staged MFMA + sum(exp), 64-col rounds, counted vmcnt ----
// grid (32 rowblocks, 24 colsplits) = 768 blocks = 3/CU.
__global__ __launch_bounds__(256)
__attribute__((amdgpu_waves_per_eu(3, 3)))
void k_simlse(
    const uint16_t* __restrict__ znA, const uint16_t* __restrict__ znB,
    float* __restrict__ partial)
{
    __shared__ __align__(16) char lds[3][TILEB];   // 48 KB, 3-deep ring

    const char* zA = (const char*)znA;
    const char* zB = (const char*)znB;
    int tid  = threadIdx.x;
    int lane = tid & 63;
    int wid  = tid >> 6;
    int lo16 = lane & 15;
    int hi4  = lane >> 4;
    int rowBase = blockIdx.x * BRT + wid * 64;

    // A fragments (prescaled by K1): 4 row-tiles x 4 K-frags = 64 regs.
    u32x4 a[4][4];
#pragma unroll
    for (int rt = 0; rt < 4; ++rt) {
        const char* ap = zA + (size_t)(rowBase + rt * 16 + lo16) * ROWB + hi4 * 16;
#pragma unroll
        for (int kf = 0; kf < 4; ++kf)
            a[rt][kf] = *(const u32x4*)(ap + kf * 64);
    }

    float rs[4][4];
#pragma unroll
    for (int rt = 0; rt < 4; ++rt)
#pragma unroll
        for (int r = 0; r < 4; ++r) rs[rt][r] = 0.f;

    // ragged 64-col tile range for this split (5 or 6 tiles)
    int t0 = (CT64 * blockIdx.y) / CSPL;
    int t1 = (CT64 * (blockIdx.y + 1)) / CSPL;
    int nt = t1 - t0;

    // per-lane inverse-swizzled global source; same swizzle bits for every
    // 4 KB quarter (row&7 == (tid>>4)&7 independent of the quarter index)
    const char* gsrc = zB + ((tid * 16) ^ (((tid >> 4) & 7) << 4));
    int xorv = (lo16 & 7) << 4;        // read-side swizzle

#define STAGE(sel, tt) do {                                                    \
        const char* g_ = gsrc + (size_t)(tt) * TILEB;                          \
        char* l_ = &lds[sel][wid * 1024];                                      \
        gload_lds16(g_,         l_);                                           \
        gload_lds16(g_ +  4096, l_ +  4096);                                   \
        gload_lds16(g_ +  8192, l_ +  8192);                                   \
        gload_lds16(g_ + 12288, l_ + 12288);                                   \
    } while (0)

#define SUBTILE(sel, ct) do {                                                  \
        const char* lb_ = &lds[sel][(ct) * 4096 + lo16 * 256];                 \
        u32x4 bf0 = *(const u32x4*)(lb_ + ((hi4 * 16 +   0) ^ xorv));          \
        u32x4 bf1 = *(const u32x4*)(lb_ + ((hi4 * 16 +  64) ^ xorv));          \
        u32x4 bf2 = *(const u32x4*)(lb_ + ((hi4 * 16 + 128) ^ xorv));          \
        u32x4 bf3 = *(const u32x4*)(lb_ + ((hi4 * 16 + 192) ^ xorv));          \
        f32x4 A0 = {0.f,0.f,0.f,0.f}, A1 = {0.f,0.f,0.f,0.f};                  \
        f32x4 A2 = {0.f,0.f,0.f,0.f}, A3 = {0.f,0.f,0.f,0.f};                  \
        A0 = __builtin_amdgcn_mfma_f32_16x16x32_bf16(BC8(a[0][0]), BC8(bf0), A0, 0, 0, 0); \
        A1 = __builtin_amdgcn_mfma_f32_16x16x32_bf16(BC8(a[1][0]), BC8(bf0), A1, 0, 0, 0); \
        A2 = __builtin_amdgcn_mfma_f32_16x16x32_bf16(BC8(a[2][0]), BC8(bf0), A2, 0, 0, 0); \
        A3 = __builtin_amdgcn_mfma_f32_16x16x32_bf16(BC8(a[3][0]), BC8(bf0), A3, 0, 0, 0); \
        A0 = __builtin_amdgcn_mfma_f32_16x16x32_bf16(BC8(a[0][1]), BC8(bf1), A0, 0, 0, 0); \
        A1 = __builtin_amdgcn_mfma_f32_16x16x32_bf16(BC8(a[1][1]), BC8(bf1), A1, 0, 0, 0); \
        A2 = __builtin_amdgcn_mfma_f32_16x16x32_bf16(BC8(a[2][1]), BC8(bf1), A2, 0, 0, 0); \
        A3 = __builtin_amdgcn_mfma_f32_16x16x32_bf16(BC8(a[3][1]), BC8(bf1), A3, 0, 0, 0); \
        A0 = __builtin_amdgcn_mfma_f32_16x16x32_bf16(BC8(a[0][2]), BC8(bf2), A0, 0, 0, 0); \
        A1 = __builtin_amdgcn_mfma_f32_16x16x32_bf16(BC8(a[1][2]), BC8(bf2), A1, 0, 0, 0); \
        A2 = __builtin_amdgcn_mfma_f32_16x16x32_bf16(BC8(a[2][2]), BC8(bf2), A2, 0, 0, 0); \
        A3 = __builtin_amdgcn_mfma_f32_16x16x32_bf16(BC8(a[3][2]), BC8(bf2), A3, 0, 0, 0); \
        A0 = __builtin_amdgcn_mfma_f32_16x16x32_bf16(BC8(a[0][3]), BC8(bf3), A0, 0, 0, 0); \
        A1 = __builtin_amdgcn_mfma_f32_16x16x32_bf16(BC8(a[1][3]), BC8(bf3), A1, 0, 0, 0); \
        A2 = __builtin_amdgcn_mfma_f32_16x16x32_bf16(BC8(a[2][3]), BC8(bf3), A2, 0, 0, 0); \
        A3 = __builtin_amdgcn_mfma_f32_16x16x32_bf16(BC8(a[3][3]), BC8(bf3), A3, 0, 0, 0); \
        _Pragma("unroll")                                                      \
        for (int r = 0; r < 4; ++r) {                                          \
            rs[0][r] += __builtin_amdgcn_exp2f(A0[r]);                         \
            rs[1][r] += __builtin_amdgcn_exp2f(A1[r]);                         \
            rs[2][r] += __builtin_amdgcn_exp2f(A2[r]);                         \
            rs[3][r] += __builtin_amdgcn_exp2f(A3[r]);                         \
        }                                                                      \
    } while (0)

#define COMPUTE(sel) do {                                                      \
        SUBTILE(sel, 0); SUBTILE(sel, 1);                                      \
        SUBTILE(sel, 2); SUBTILE(sel, 3);                                      \
    } while (0)

#define WAITBAR(n) do {                                                       \
        asm volatile("s_waitcnt vmcnt(" #n ")" ::: "memory");                  \
        __builtin_amdgcn_s_barrier();                                          \
        __builtin_amdgcn_sched_barrier(0);                                     \
    } while (0)

    // prologue: 2 tiles in flight (nt >= 5 always)
    STAGE(0, t0); STAGE(1, t0 + 1);

    int r = 0;
    for (; r < nt - 2; ++r) {
        WAITBAR(4);                       // tile r ready; tile r+1 in flight
        STAGE((r + 2) % 3, t0 + r + 2);   // issue next before compute
        COMPUTE(r % 3);
    }
    WAITBAR(4);                           // r = nt-2 ready (nt-1 in flight)
    COMPUTE((nt - 2) % 3);
    WAITBAR(0);                           // drain
    COMPUTE((nt - 1) % 3);

#undef STAGE
#undef SUBTILE
#undef COMPUTE
#undef WAITBAR

    // reduce row-sums across the 16 column-lanes; write per-split partials
#pragma unroll
    for (int rt = 0; rt < 4; ++rt)
#pragma unroll
        for (int r2 = 0; r2 < 4; ++r2) {
            float s = rs[rt][r2];
            s += __shfl_xor(s, 1);  s += __shfl_xor(s, 2);
            s += __shfl_xor(s, 4);  s += __shfl_xor(s, 8);
            if (lo16 == 0) {
                int row = rowBase + rt * 16 + hi4 * 4 + r2;
                partial[blockIdx.y * NROWS + row] = s;
            }
        }
}

// ---- kernel 3: per-row lse - pos, subtract diag, block partial sums --------
__global__ __launch_bounds__(256) void k_finalize(
    const uint16_t* __restrict__ znA, const uint16_t* __restrict__ znB,
    const float* __restrict__ partial, float* __restrict__ blocksum)
{
    int tid = threadIdx.x;
    int i = blockIdx.x * 256 + tid;

    float S = 0.f;
#pragma unroll
    for (int cs = 0; cs < CSPL; ++cs) S += partial[cs * NROWS + i];

    int j = (i + BROWS) & (NROWS - 1);
    const uint4* rAi = (const uint4*)((const char*)znA + (size_t)i * ROWB);
    const uint4* rBi = (const uint4*)((const char*)znB + (size_t)i * ROWB);
    const uint4* rBj = (const uint4*)((const char*)znB + (size_t)j * ROWB);
    float adot = 0.f;   // K1 * <zn_i, zn_j>
    float sdot = 0.f;   // K1 * <zn_i, zn_i>
#pragma unroll
    for (int c = 0; c < 16; ++c) {
        uint4 ua = rAi[c], ub = rBi[c], vb = rBj[c];
        const uint32_t* pa = (const uint32_t*)&ua;
        const uint32_t* pb = (const uint32_t*)&ub;
        const uint32_t* pv = (const uint32_t*)&vb;
#pragma unroll
        for (int q = 0; q < 4; ++q) {
            float a0 = bf2f((uint16_t)(pa[q] & 0xffffu)), a1 = bf2f((uint16_t)(pa[q] >> 16));
            float b0 = bf2f((uint16_t)(pb[q] & 0xffffu)), b1 = bf2f((uint16_t)(pb[q] >> 16));
            float v0 = bf2f((uint16_t)(pv[q] & 0xffffu)), v1 = bf2f((uint16_t)(pv[q] >> 16));
            adot += a0 * v0 + a1 * v1;
            sdot += a0 * b0 + a1 * b1;
        }
    }
    S -= __builtin_amdgcn_exp2f(sdot);                  // remove diagonal term
    float c = LN2F * (__builtin_amdgcn_logf(S) - adot); // ln(S) - pos/T

#pragma unroll
    for (int off = 1; off < 64; off <<= 1) c += __shfl_xor(c, off);
    __shared__ float wsum[4];
    int lane = tid & 63, wid = tid >> 6;
    if (lane == 0) wsum[wid] = c;
    __syncthreads();
    if (tid == 0) blocksum[blockIdx.x] = wsum[0] + wsum[1] + wsum[2] + wsum[3];
}

// ---- kernel 4: final scalar -------------------------------------------------
__global__ __launch_bounds__(64) void k_reduce(
    const float* __restrict__ blocksum, float* __restrict__ out)
{
    int tid = threadIdx.x;
    float v = (tid < 32) ? blocksum[tid] : 0.f;
#pragma unroll
    for (int off = 1; off < 64; off <<= 1) v += __shfl_xor(v, off);
    if (tid == 0) out[0] = v * (1.0f / (float)NROWS);
}

extern "C" void kernel_launch(void* const* d_in, const int* in_sizes, int n_in,
                              void* d_out, int out_size, void* d_ws, size_t ws_size,
                              hipStream_t stream)
{
    const float* zi = (const float*)d_in[0];
    const float* zj = (const float*)d_in[1];
    float* out = (float*)d_out;

    char* ws = (char*)d_ws;
    uint16_t* znA      = (uint16_t*)ws;                                   // 2 MB
    uint16_t* znB      = (uint16_t*)(ws + (size_t)NROWS * ROWB);          // 2 MB
    float*    partial  = (float*)(ws + 2 * (size_t)NROWS * ROWB);         // 768 KB
    float*    blocksum = (float*)(ws + 2 * (size_t)NROWS * ROWB
                                     + (size_t)CSPL * NROWS * 4);

    k_normalize<<<dim3(256), dim3(256), 0, stream>>>(zi, zj, znA, znB);
    k_simlse  <<<dim3(32, CSPL), dim3(256), 0, stream>>>(znA, znB, partial);
    k_finalize<<<dim3(32), dim3(256), 0, stream>>>(znA, znB, partial, blocksum);
    k_reduce  <<<dim3(1), dim3(64), 0, stream>>>(blocksum, out);
}